// Round 2
// baseline (121.552 us; speedup 1.0000x reference)
//
#include <hip/hip_runtime.h>

// FactorizedEmbedding: out[m, :] = embed_vocab[x[m], :] @ embed_hidden
//   x  : [16384] int token ids       ev : [128000, 128] fp32
//   eh : [128, 1024] fp32            out: [16384, 1024] fp32
//
// Split-bf16 MFMA: f = hi + lo (both exactly representable in bf16, via
// truncation; |f - hi - lo| < 2^-16 |f|). out = ah*bh + ah*bl + al*bh in
// fp32-accumulating v_mfma_f32_16x16x32_bf16 (inline asm; A/B use identical
// per-lane k-patterns so any HW k-permutation cancels).
//
// Tile: 128x128 per block, 4 waves (2x2), wave tile 64x64 = 4x4 frags of
// 16x16. K=128 staged in two 64-halves -> LDS 64 KiB -> 2 blocks/CU.
// LDS rows are 128 B; 16B-granule XOR swizzle (granule ^= row&7) makes every
// b128 read/write land 8 lanes per 4-bank group (conflict-free minimum).

using f32x4 = __attribute__((ext_vector_type(4))) float;
using i32x4 = __attribute__((ext_vector_type(4))) int;

constexpr int EMB = 128;
constexpr int HID = 1024;

// 8 fp32 -> 4 packed u32 of bf16-hi and 4 of bf16-lo (truncation split).
__device__ inline void cvt8(const float f[8], i32x4& hi, i32x4& lo) {
    unsigned h[8], l[8];
#pragma unroll
    for (int e = 0; e < 8; ++e) {
        unsigned fb = __float_as_uint(f[e]);
        unsigned hb = fb & 0xFFFF0000u;          // bf16 hi (truncate)
        float r = f[e] - __uint_as_float(hb);    // exact residual
        unsigned lb = __float_as_uint(r) & 0xFFFF0000u;  // bf16 lo
        h[e] = hb; l[e] = lb;
    }
#pragma unroll
    for (int p = 0; p < 4; ++p) {
        hi[p] = (int)((h[2*p] >> 16) | h[2*p+1]);   // elem k low half, k+1 high
        lo[p] = (int)((l[2*p] >> 16) | l[2*p+1]);
    }
}

__device__ inline f32x4 mfma_bf16(i32x4 a, i32x4 b, f32x4 c) {
    f32x4 d;
    asm volatile("v_mfma_f32_16x16x32_bf16 %0, %1, %2, %3"
                 : "=v"(d) : "v"(a), "v"(b), "0"(c));
    return d;
}

__global__ __launch_bounds__(256, 2)
void femb_mfma(const int* __restrict__ x,
               const float* __restrict__ ev,
               const float* __restrict__ eh,
               float* __restrict__ out, int mtiles)
{
    __shared__ __align__(16) char lds[65536];
    char* Ah = lds;              // [tok:128][k:64] bf16, 128 B rows, swizzled
    char* Al = lds + 16384;
    char* Bh = lds + 32768;      // [n:128][k:64] bf16 (B transposed)
    char* Bl = lds + 49152;

    const int tid  = threadIdx.x;
    const int bid  = blockIdx.x;
    const int mt   = bid % mtiles;          // same-mt blocks: bid ≡ mt (mod 8) -> same XCD
    const int nt   = bid / mtiles;
    const long m0  = (long)mt * 128;
    const long n0  = (long)nt * 128;
    const int lane = tid & 63;
    const int wid  = tid >> 6;
    const int wm   = wid >> 1, wn = wid & 1;
    const int rl   = lane & 15, g = lane >> 4;

    f32x4 acc[4][4];
#pragma unroll
    for (int i = 0; i < 4; ++i)
#pragma unroll
        for (int j = 0; j < 4; ++j) acc[i][j] = (f32x4){0.f, 0.f, 0.f, 0.f};

    for (int h = 0; h < 2; ++h) {           // two K-halves of 64
        if (h) __syncthreads();             // LDS rewrite safety

        // ---- stage A: gather 128 rows x 64 k, convert to hi/lo bf16 ----
#pragma unroll
        for (int i = 0; i < 4; ++i) {
            const int c   = tid + 256 * i;  // 0..1023: [tok:128][k8:8]
            const int tok = c >> 3, k8 = c & 7;
            const long id = x[m0 + tok];
            const float* src = ev + id * EMB + h * 64 + k8 * 8;
            float f[8];
            *(float4*)(f)     = *(const float4*)(src);
            *(float4*)(f + 4) = *(const float4*)(src + 4);
            i32x4 hi, lo; cvt8(f, hi, lo);
            const int off = tok * 128 + ((k8 * 16) ^ ((tok & 7) << 4));
            *(i32x4*)(Ah + off) = hi;
            *(i32x4*)(Al + off) = lo;
        }
        // ---- stage B: 64 k x 128 n of eh, transposed to [n][k] ----
#pragma unroll
        for (int i = 0; i < 4; ++i) {
            const int c  = tid + 256 * i;   // [k8:8][n:128]
            const int n  = c & 127, k8 = c >> 7;
            float f[8];
#pragma unroll
            for (int j = 0; j < 8; ++j)
                f[j] = eh[(long)(h * 64 + k8 * 8 + j) * HID + n0 + n];
            i32x4 hi, lo; cvt8(f, hi, lo);
            const int off = n * 128 + ((k8 * 16) ^ ((n & 7) << 4));
            *(i32x4*)(Bh + off) = hi;
            *(i32x4*)(Bl + off) = lo;
        }
        __syncthreads();

        // ---- compute: 2 k-steps of 32 per half ----
#pragma unroll
        for (int kk = 0; kk < 2; ++kk) {
            i32x4 a_h[4], a_l[4], b_h[4], b_l[4];
#pragma unroll
            for (int mf = 0; mf < 4; ++mf) {
                const int row = wm * 64 + mf * 16 + rl;
                const int off = row * 128 + ((kk * 64 + g * 16) ^ ((row & 7) << 4));
                a_h[mf] = *(const i32x4*)(Ah + off);
                a_l[mf] = *(const i32x4*)(Al + off);
            }
#pragma unroll
            for (int nf = 0; nf < 4; ++nf) {
                const int nr  = wn * 64 + nf * 16 + rl;
                const int off = nr * 128 + ((kk * 64 + g * 16) ^ ((nr & 7) << 4));
                b_h[nf] = *(const i32x4*)(Bh + off);
                b_l[nf] = *(const i32x4*)(Bl + off);
            }
#pragma unroll
            for (int mf = 0; mf < 4; ++mf)
#pragma unroll
                for (int nf = 0; nf < 4; ++nf) {
                    acc[mf][nf] = mfma_bf16(a_h[mf], b_h[nf], acc[mf][nf]);
                    acc[mf][nf] = mfma_bf16(a_h[mf], b_l[nf], acc[mf][nf]);
                    acc[mf][nf] = mfma_bf16(a_l[mf], b_h[nf], acc[mf][nf]);
                }
        }
    }

    // ---- epilogue: C/D layout col = lane&15, row = (lane>>4)*4 + j ----
#pragma unroll
    for (int mf = 0; mf < 4; ++mf)
#pragma unroll
        for (int j = 0; j < 4; ++j) {
            const long row = m0 + wm * 64 + mf * 16 + g * 4 + j;
            float* dst = out + row * HID + n0 + wn * 64 + rl;
#pragma unroll
            for (int nf = 0; nf < 4; ++nf) dst[nf * 16] = acc[mf][nf][j];
        }
}

extern "C" void kernel_launch(void* const* d_in, const int* in_sizes, int n_in,
                              void* d_out, int out_size, void* d_ws, size_t ws_size,
                              hipStream_t stream) {
    const int*   x   = (const int*)d_in[0];
    const float* ev  = (const float*)d_in[1];
    const float* eh  = (const float*)d_in[2];
    float*       out = (float*)d_out;

    const int M      = in_sizes[0];          // 16384
    const int mtiles = M / 128;              // 128
    const int grid   = mtiles * (HID / 128); // 1024
    femb_mfma<<<grid, 256, 0, stream>>>(x, ev, eh, out, mtiles);
}